// Round 19
// baseline (100.166 us; speedup 1.0000x reference)
//
#include <hip/hip_runtime.h>
#include <hip/hip_bf16.h>

#define B_  2
#define S_  2048
#define D_  1024
#define H_  16
#define HD_ 64
#define BS_ (B_*S_)   // 4096

typedef __attribute__((ext_vector_type(8))) short bf16x8;
typedef __attribute__((ext_vector_type(4))) float f32x4;
typedef __attribute__((ext_vector_type(4))) float float4v;
typedef __attribute__((ext_vector_type(4))) unsigned short ushort4v;
typedef __attribute__((ext_vector_type(2))) unsigned int uint2v;

// finer split-kv: chunk <= 11 tiles; nc(qb) = ceil((qb+1)/11); chunk ci covers
// [n*ci/nc, n*(ci+1)/nc). 63 items/bh = 2016 blocks (1.6x oversub), longest-first.
__constant__ unsigned char TQ63[63] = {
  31,31,30,21,21,20,10,                                  // len 11
  31,30,30,29,29,29,28,28,27,20,19,19,18,9,              // len 10
  28,27,27,26,26,26,25,25,24,18,17,17,16,8,              // len 9
  25,24,24,23,23,23,22,22,16,15,15,14,7,                 // len 8
  22,14,13,13,12,6,                                      // len 7
  12,11,11,5,                                            // len 6
  4,3,2,1,0};                                            // len <=5
__constant__ unsigned char TC63[63] = {
  1,2,2,0,1,1,0,
  0,0,1,0,1,2,1,2,2,0,0,1,1,0,
  0,0,1,0,1,2,1,2,2,0,0,1,1,0,
  0,0,1,0,1,2,1,2,0,0,1,1,0,
  0,0,0,1,1,0,
  0,0,1,0,
  0,0,0,0,0};

__device__ __forceinline__ int slot_base(int qb) {       // prefix of nc over qb=11..31
  return (qb <= 21) ? (qb - 11) * 2 : 22 + 3 * (qb - 22);
}

__device__ __forceinline__ unsigned short f2bf(float f) {
  union { float f; unsigned int u; } v; v.f = f;
  unsigned int u = v.u;
  return (unsigned short)((u + 0x7fffu + ((u >> 16) & 1u)) >> 16);  // RNE
}
__device__ __forceinline__ float bf2f(unsigned short u) {
  union { unsigned int i; float f; } v; v.i = ((unsigned int)u) << 16; return v.f;
}
__device__ __forceinline__ unsigned int cvtpk(float lo, float hi) {
  unsigned int r;
  asm("v_cvt_pk_bf16_f32 %0, %1, %2" : "=v"(r) : "v"(lo), "v"(hi));
  return r;
}

// cross-lane row swaps via permlane (VALU pipe; R6-R12 bench-proven helpers).
__device__ __forceinline__ void plswap16u(unsigned int& a, unsigned int& b) {
#if __has_builtin(__builtin_amdgcn_permlane16_swap)
  uint2v r = __builtin_amdgcn_permlane16_swap(a, b, false, false);
  a = r[0]; b = r[1];
#else
  asm volatile("v_permlane16_swap_b32 %0, %1" : "+v"(a), "+v"(b));
#endif
}
__device__ __forceinline__ void plswap32u(unsigned int& a, unsigned int& b) {
#if __has_builtin(__builtin_amdgcn_permlane32_swap)
  uint2v r = __builtin_amdgcn_permlane32_swap(a, b, false, false);
  a = r[0]; b = r[1];
#else
  asm volatile("v_permlane32_swap_b32 %0, %1" : "+v"(a), "+v"(b));
#endif
}

__device__ __forceinline__ void gload16(const void* g, void* l) {
  __builtin_amdgcn_global_load_lds((const __attribute__((address_space(1))) void*)g,
                                   (__attribute__((address_space(3))) void*)l, 16, 0, 0);
}

__device__ __forceinline__ f32x4 mfma16(bf16x8 a, bf16x8 b, f32x4 c) {
  return __builtin_amdgcn_mfma_f32_16x16x32_bf16(a, b, c, 0, 0, 0);
}

// ---------------- merged prep: x fp32->bf16 (blocks 0..2047) + W transpose-convert ----------------
__global__ __launch_bounds__(256) void k_prep(const float* __restrict__ x, unsigned short* __restrict__ xb,
                                              const float* __restrict__ w0, const float* __restrict__ w1,
                                              const float* __restrict__ w2, const float* __restrict__ w3,
                                              unsigned short* __restrict__ o0, unsigned short* __restrict__ o1,
                                              unsigned short* __restrict__ o2, unsigned short* __restrict__ o3) {
  const int bid = blockIdx.x;
  if (bid < 2048) {                            // convert part
    int i = bid * 256 + threadIdx.x;
    float4v a = ((const float4v*)x)[2*i];
    float4v b = ((const float4v*)x)[2*i + 1];
    union { bf16x8 v; unsigned short u[8]; } o;
#pragma unroll
    for (int j = 0; j < 4; ++j) { o.u[j] = f2bf(a[j]); o.u[4+j] = f2bf(b[j]); }
    ((bf16x8*)xb)[i] = o.v;
    return;
  }
  // weight transpose part: W (K x N) f32 -> Wt (N x K) bf16
  const int wid = bid - 2048;
  const int xx = wid & 15, yy = (wid >> 4) & 15, zz = wid >> 8;
  const float* w = zz == 0 ? w0 : zz == 1 ? w1 : zz == 2 ? w2 : w3;
  unsigned short* o = zz == 0 ? o0 : zz == 1 ? o1 : zz == 2 ? o2 : o3;
  __shared__ unsigned short til[64][68];
  const int n0 = xx * 64, k0 = yy * 64;
  const int t = threadIdx.x, r = t >> 4, c4 = t & 15;
#pragma unroll
  for (int i = 0; i < 4; ++i) {
    float4v v = *(const float4v*)(w + (size_t)(k0 + i*16 + r) * D_ + n0 + c4*4);
#pragma unroll
    for (int j = 0; j < 4; ++j) til[i*16 + r][c4*4 + j] = f2bf(v[j]);
  }
  __syncthreads();
#pragma unroll
  for (int i = 0; i < 4; ++i) {
    ushort4v u;
#pragma unroll
    for (int j = 0; j < 4; ++j) u[j] = til[c4*4 + j][i*16 + r];
    *(ushort4v*)(o + (size_t)(n0 + i*16 + r) * D_ + k0 + c4*4) = u;
  }
}

// ---------------- GEMM: A (M x K) bf16, Bt (N x K) bf16 -> C (M x N) ----------------
template <int MODE, typename OutT>
__device__ __forceinline__ void gemm_body(const unsigned short* __restrict__ A,
                                          const unsigned short* __restrict__ Bt,
                                          OutT* __restrict__ C,
                                          unsigned short* As, unsigned short* Bs,
                                          int M, int N, int K, int mblk, int nblk) {
  const int tid = threadIdx.x;
  const int w = tid >> 6, lane = tid & 63;
  const int lg = lane >> 4, li = lane & 15;
  const int m0 = mblk * 128, n0 = nblk * 128;
  const int wr = (w >> 1) * 64, wc = (w & 1) * 64;
  f32x4 acc[4][4] = {};
  for (int kt = 0; kt < K; kt += 64) {
#pragma unroll
    for (int i = 0; i < 4; ++i) {
      int c = (i*4 + w) * 64 + lane;           // 0..1023, 16B chunks
      int r = c >> 3, kc = c & 7;
      int off = ((kc ^ (r & 7)) << 3);         // pre-swizzled global source (rule #21)
      gload16(A  + (size_t)(m0 + r) * K + kt + off, (char*)As + (i*4 + w) * 1024);
      gload16(Bt + (size_t)(n0 + r) * K + kt + off, (char*)Bs + (i*4 + w) * 1024);
    }
    __syncthreads();
#pragma unroll
    for (int ks = 0; ks < 2; ++ks) {
      bf16x8 af[4], bfr[4];
#pragma unroll
      for (int m = 0; m < 4; ++m) {
        int rr = wr + m*16 + li;
        int ch = (ks*4 + lg) ^ (rr & 7);
        af[m] = *(const bf16x8*)((const char*)As + rr*128 + ch*16);
      }
#pragma unroll
      for (int n = 0; n < 4; ++n) {
        int rr = wc + n*16 + li;
        int ch = (ks*4 + lg) ^ (rr & 7);
        bfr[n] = *(const bf16x8*)((const char*)Bs + rr*128 + ch*16);
      }
#pragma unroll
      for (int m = 0; m < 4; ++m)
#pragma unroll
        for (int n = 0; n < 4; ++n)
          acc[m][n] = mfma16(af[m], bfr[n], acc[m][n]);
    }
    __syncthreads();
  }
#pragma unroll
  for (int m = 0; m < 4; ++m)
#pragma unroll
    for (int n = 0; n < 4; ++n) {
      if (MODE == 2) {                         // V: store transposed into (b,h,hd,s)
        int gr = m0 + wr + m*16 + lg*4;        // rows gr..gr+3 (s-consecutive)
        int gc = n0 + wc + n*16 + li;          // col = h*64 + d
        int bb = gr >> 11, ss = gr & 2047, hh = gc >> 6, dd = gc & 63;
        unsigned short* p = (unsigned short*)C + ((size_t)((bb*H_ + hh)*HD_ + dd)) * S_ + ss;
        uint2v o2;
        o2[0] = cvtpk(acc[m][n][0], acc[m][n][1]);
        o2[1] = cvtpk(acc[m][n][2], acc[m][n][3]);
        *(uint2v*)p = o2;
      } else {
#pragma unroll
        for (int j = 0; j < 4; ++j) {
          int row = m0 + wr + m*16 + lg*4 + j; // HW-verified C layout (m89)
          int col = n0 + wc + n*16 + li;
          if (MODE == 1) ((float*)C)[(size_t)row * N + col] = acc[m][n][j];
          else ((unsigned short*)C)[(size_t)row * N + col] = f2bf(acc[m][n][j]);
        }
      }
    }
}

__global__ __launch_bounds__(256, 3) void k_qkv(const unsigned short* __restrict__ xb,
    const unsigned short* __restrict__ wqt, const unsigned short* __restrict__ wkt,
    const unsigned short* __restrict__ wvt,
    unsigned short* __restrict__ Qb, unsigned short* __restrict__ Kb, unsigned short* __restrict__ Vtb) {
  __shared__ unsigned short As[128 * 64];
  __shared__ unsigned short Bs[128 * 64];
  const int z = blockIdx.z;
  if (z == 2) {
    gemm_body<2, unsigned short>(xb, wvt, Vtb, As, Bs, BS_, D_, D_, blockIdx.x, blockIdx.y);
  } else {
    gemm_body<0, unsigned short>(xb, z ? wkt : wqt, z ? Kb : Qb, As, Bs, BS_, D_, D_, blockIdx.x, blockIdx.y);
  }
}

// ---------------- out GEMM: 128x64 tile -> grid (32,16) = 512 blocks = 2/CU (R18-proven) --------
__global__ __launch_bounds__(256, 2) void k_out(const unsigned short* __restrict__ AO,
                                                const unsigned short* __restrict__ wot,
                                                float* __restrict__ out) {
  __shared__ unsigned short As[128 * 64];     // 16KB
  __shared__ unsigned short Bs[64 * 64];      // 8KB
  const int tid = threadIdx.x;
  const int w = tid >> 6, lane = tid & 63;
  const int lg = lane >> 4, li = lane & 15;
  const int m0 = blockIdx.x * 128, n0 = blockIdx.y * 64;
  f32x4 acc[2][4] = {};
  for (int kt = 0; kt < D_; kt += 64) {
#pragma unroll
    for (int i = 0; i < 4; ++i) {             // A: 1024 chunks (gemm_body pattern)
      int c = (i*4 + w) * 64 + lane;
      int r = c >> 3, kc = c & 7;
      int off = ((kc ^ (r & 7)) << 3);
      gload16(AO + (size_t)(m0 + r) * D_ + kt + off, (char*)As + (i*4 + w) * 1024);
    }
#pragma unroll
    for (int i = 0; i < 2; ++i) {             // B: 512 chunks (attn K-staging pattern)
      int c = (i*4 + w) * 64 + lane;
      int r = c >> 3, kc = c & 7;
      int off = ((kc ^ (r & 7)) << 3);
      gload16(wot + (size_t)(n0 + r) * D_ + kt + off, (char*)Bs + (i*4 + w) * 1024);
    }
    __syncthreads();
#pragma unroll
    for (int ks = 0; ks < 2; ++ks) {
      bf16x8 af[2], bfr[4];
#pragma unroll
      for (int m = 0; m < 2; ++m) {
        int rr = w*32 + m*16 + li;
        int ch = (ks*4 + lg) ^ (rr & 7);
        af[m] = *(const bf16x8*)((const char*)As + rr*128 + ch*16);
      }
#pragma unroll
      for (int n = 0; n < 4; ++n) {
        int rr = n*16 + li;
        int ch = (ks*4 + lg) ^ (rr & 7);
        bfr[n] = *(const bf16x8*)((const char*)Bs + rr*128 + ch*16);
      }
#pragma unroll
      for (int m = 0; m < 2; ++m)
#pragma unroll
        for (int n = 0; n < 4; ++n)
          acc[m][n] = mfma16(af[m], bfr[n], acc[m][n]);
    }
    __syncthreads();
  }
#pragma unroll
  for (int m = 0; m < 2; ++m)
#pragma unroll
    for (int n = 0; n < 4; ++n)
#pragma unroll
      for (int j = 0; j < 4; ++j) {
        int row = m0 + w*32 + m*16 + lg*4 + j; // HW-verified C layout (m89)
        int col = n0 + n*16 + li;
        out[(size_t)row * D_ + col] = acc[m][n][j];
      }
}

// ---------------- flash attention, causal — fine split-kv (<=11 tiles), R15 inner loop ----------
// grid (32 bh, 63 items) = 2016 blocks, 1.6x oversub at 5/CU -> LPT refill pool sustains
// occupancy (R18 limiter: 48-item pool = 1.2x oversub -> drain-dominated, VALUBusy 50%).
__global__ __launch_bounds__(256, 5) void k_attn(const unsigned short* __restrict__ Q,
                                                 const unsigned short* __restrict__ K,
                                                 const unsigned short* __restrict__ Vt,
                                                 unsigned short* __restrict__ AO,
                                                 unsigned short* __restrict__ Opart,
                                                 float* __restrict__ ML) {
  __shared__ unsigned short Ks[2 * 64 * 64];  // [buf][kv][hd], chunk-swizzled
  __shared__ unsigned short Vs[2 * 64 * 64];  // [buf][hd][kv], chunk-swizzled
  const int bh = blockIdx.x;                  // XCD = linear%8 -> all items of a head share L2
  const int y = blockIdx.y;
  const int qb = TQ63[y], ci = TC63[y];
  const int n = qb + 1;
  const int nc = (n + 10) / 11;               // chunks for this qb
  const int kt0 = (n * ci) / nc;
  const int kt1 = (n * (ci + 1)) / nc;
  const bool split = (nc > 1);
  const int b = bh >> 4, h = bh & 15;
  const int tid = threadIdx.x, w = tid >> 6, lane = tid & 63;
  const int lg = lane >> 4, li = lane & 15;
  const float SC2 = 0.18033688f;              // (1/sqrt(64)) * log2(e)

  // ones A-fragment for the l contraction (bf16 1.0 = 0x3f80)
  union { bf16x8 v; unsigned short u[8]; } onesu;
#pragma unroll
  for (int j = 0; j < 8; ++j) onesu.u[j] = 0x3f80;
  const bf16x8 onesv = onesu.v;

  // Q fragment (B-operand): row = q = li, k-chunks lg*8 (+0 / +32); pre-scaled by SC2.
  const int qglob = qb*64 + w*16 + li;
  const unsigned short* qptr = Q + (size_t)(b*S_ + qglob) * D_ + h*HD_;
  union { bf16x8 v; unsigned short u[8]; } q0u, q1u;
  q0u.v = *(const bf16x8*)(qptr + lg*8);
  q1u.v = *(const bf16x8*)(qptr + 32 + lg*8);
#pragma unroll
  for (int j = 0; j < 8; ++j) {
    q0u.u[j] = f2bf(bf2f(q0u.u[j]) * SC2);
    q1u.u[j] = f2bf(bf2f(q1u.u[j]) * SC2);
  }
  const bf16x8 qf0 = q0u.v, qf1 = q1u.v;

  // K-fragment LDS offsets: row=li (within kj block), chunk ks*4+lg
  int kfoff[2];
#pragma unroll
  for (int ks = 0; ks < 2; ++ks)
    kfoff[ks] = li*128 + (((ks*4 + lg) ^ (li & 7)) << 4);

  // staging: per-lane global offsets + advancing base pointers (R4-proven 4-wave split)
  int kofs[2], vofs[2], lofs[2];
#pragma unroll
  for (int i = 0; i < 2; ++i) {
    int c = (i*4 + w) * 64 + lane;            // 0..511, 16B chunks
    int r = c >> 3, kc = c & 7;
    int off = ((kc ^ (r & 7)) << 3);          // pre-swizzled global source (rule #21)
    kofs[i] = r * D_ + off;
    vofs[i] = r * S_ + off;
    lofs[i] = (i*4 + w) * 1024;
  }
  const unsigned short* kg = K  + (size_t)(b*S_ + kt0*64) * D_ + h*HD_;  // += 64*D_ per tile
  const unsigned short* vg = Vt + (size_t)bh * HD_ * S_ + kt0*64;        // += 64 per tile

  f32x4 oacc[4] = {};                          // oacc[nn][j] = O[q=li][d=nn*16+lg*4+j], unnormalized
  f32x4 lacc = {};                             // lacc[j] = l[q=li] (all j equal)

  auto stage = [&](int bsel, const unsigned short* kp, const unsigned short* vp) {
    char* KsB = (char*)Ks + bsel * 8192;
    char* VsB = (char*)Vs + bsel * 8192;
#pragma unroll
    for (int i = 0; i < 2; ++i) {
      gload16(kp + kofs[i], KsB + lofs[i]);
      gload16(vp + vofs[i], VsB + lofs[i]);
    }
  };

  stage(0, kg, vg);
  __syncthreads();

  for (int kt = kt0; kt < kt1; ++kt) {
    const int cur = (kt - kt0) & 1;
    if (kt + 1 < kt1) {                        // prefetch overlaps this tile's compute
      kg += 64 * D_; vg += 64;
      stage(cur ^ 1, kg, vg);
    }
    const char* KsB = (const char*)Ks + cur * 8192;
    const char* VsB = (const char*)Vs + cur * 8192;

    // S^T = K Q^T : sc[kj][j] = S[q=li][kv=kj*16+lg*4+j]  (log2-scaled)
    f32x4 sc[4];
    __builtin_amdgcn_s_setprio(1);
#pragma unroll
    for (int kj = 0; kj < 4; ++kj) {
      f32x4 t = {};
      t = mfma16(*(const bf16x8*)(KsB + kj*2048 + kfoff[0]), qf0, t);
      t = mfma16(*(const bf16x8*)(KsB + kj*2048 + kfoff[1]), qf1, t);
      sc[kj] = t;
    }
    __builtin_amdgcn_s_setprio(0);

    if (kt == qb) {                            // causal mask (diag tile; last chunk only)
      const int qloc = w*16 + li;
#pragma unroll
      for (int kj = 0; kj < 4; ++kj)
#pragma unroll
        for (int j = 0; j < 4; ++j)
          if (kj*16 + lg*4 + j > qloc) sc[kj][j] = -1e30f;
    }

    // softmax weights, no max subtraction (bounded scores): P = exp2(S2) <= 2^9
    f32x4 pvv[4];
#pragma unroll
    for (int kj = 0; kj < 4; ++kj)
#pragma unroll
      for (int j = 0; j < 4; ++j)
        pvv[kj][j] = exp2f(sc[kj][j]);         // masked entries underflow to 0

    // P -> bf16 dwords d[kj][p] -> in-register fragment via permlane swaps (R8-proven)
    unsigned int d00 = cvtpk(pvv[0][0], pvv[0][1]), d01 = cvtpk(pvv[0][2], pvv[0][3]);
    unsigned int d10 = cvtpk(pvv[1][0], pvv[1][1]), d11 = cvtpk(pvv[1][2], pvv[1][3]);
    unsigned int d20 = cvtpk(pvv[2][0], pvv[2][1]), d21 = cvtpk(pvv[2][2], pvv[2][3]);
    unsigned int d30 = cvtpk(pvv[3][0], pvv[3][1]), d31 = cvtpk(pvv[3][2], pvv[3][3]);
    plswap32u(d00, d10); plswap16u(d00, d10);
    plswap32u(d01, d11); plswap16u(d01, d11);
    plswap32u(d20, d30); plswap16u(d20, d30);
    plswap32u(d21, d31); plswap16u(d21, d31);
    union { bf16x8 v; unsigned int d[4]; } p0, p1;
    p0.d[0] = d00; p0.d[1] = d01; p0.d[2] = d10; p0.d[3] = d11;
    p1.d[0] = d20; p1.d[1] = d21; p1.d[2] = d30; p1.d[3] = d31;

    // O^T += V^T P^T ; l += ones . P  (matrix pipe computes the row-sums too)
    __builtin_amdgcn_s_setprio(1);
    lacc = mfma16(onesv, p0.v, lacc);
    lacc = mfma16(onesv, p1.v, lacc);
#pragma unroll
    for (int nn = 0; nn < 4; ++nn) {
      int vr = nn*16 + li;
      int ch0 = lg ^ (vr & 7), ch1 = (4 + lg) ^ (vr & 7);
      oacc[nn] = mfma16(*(const bf16x8*)(VsB + vr*128 + ch0*16), p0.v, oacc[nn]);
      oacc[nn] = mfma16(*(const bf16x8*)(VsB + vr*128 + ch1*16), p1.v, oacc[nn]);
    }
    __builtin_amdgcn_s_setprio(0);
    __syncthreads();   // drains prefetch vmcnt + publishes; next iter reads buf^1
  }

  // epilogue — l is already fully reduced per-lane (lacc[0] == row-sum for q=li)
  const float l = lacc[0];
  if (!split) {                                // direct: normalize + store bf16
    const float inv = 1.0f / l;
    unsigned short* aorow = AO + (size_t)(b*S_ + qglob) * D_ + h*HD_;
#pragma unroll
    for (int nn = 0; nn < 4; ++nn) {
      uint2v o2;
      o2[0] = cvtpk(oacc[nn][0] * inv, oacc[nn][1] * inv);
      o2[1] = cvtpk(oacc[nn][2] * inv, oacc[nn][3] * inv);
      *(uint2v*)(aorow + nn*16 + lg*4) = o2;
    }
  } else {                                     // partial: unnormalized O bf16 + l f32
    const int slot = bh * 52 + slot_base(qb) + ci;
    unsigned short* ob = Opart + (size_t)slot * 4096 + (w*16 + li) * 64;
#pragma unroll
    for (int nn = 0; nn < 4; ++nn) {
      uint2v o2;
      o2[0] = cvtpk(oacc[nn][0], oacc[nn][1]);
      o2[1] = cvtpk(oacc[nn][2], oacc[nn][3]);
      *(uint2v*)(ob + nn*16 + lg*4) = o2;
    }
    if (lg == 0) ML[slot*64 + (w*16 + li)] = l;
  }
}

// ---------------- combine split-kv partials: AO[qb>=11] = (sum o_i)/(sum l_i) ----------------
__global__ __launch_bounds__(256) void k_comb(const unsigned short* __restrict__ Opart,
                                              const float* __restrict__ ML,
                                              unsigned short* __restrict__ AO) {
  const int qb = 11 + blockIdx.x;             // 11..31
  const int bh = blockIdx.y;                  // 0..31
  const int b = bh >> 4, h = bh & 15;
  const int nc = (qb + 11) / 11;              // 2 or 3
  const int s0 = bh * 52 + slot_base(qb);
  const int tid = threadIdx.x;
  const int q = tid >> 2, dg = (tid & 3) * 16;
  float l = 0.f;
  float acc[16] = {};
#pragma unroll
  for (int ci = 0; ci < 3; ++ci) {
    if (ci >= nc) break;
    const int slot = s0 + ci;
    l += ML[slot*64 + q];
    const unsigned short* o = Opart + (size_t)slot * 4096 + q*64 + dg;
    union { bf16x8 v; unsigned short u[8]; } xa, xb2;
    xa.v = *(const bf16x8*)o;  xb2.v = *(const bf16x8*)(o + 8);
#pragma unroll
    for (int j = 0; j < 8; ++j) { acc[j] += bf2f(xa.u[j]); acc[8+j] += bf2f(xb2.u[j]); }
  }
  const float inv = 1.0f / l;
  unsigned short* ao = AO + (size_t)(b*S_ + qb*64 + q) * D_ + h*HD_ + dg;
  uint2v w0, w0b, w1a, w1b;
  w0[0]  = cvtpk(acc[0]*inv,  acc[1]*inv);
  w0[1]  = cvtpk(acc[2]*inv,  acc[3]*inv);
  w0b[0] = cvtpk(acc[4]*inv,  acc[5]*inv);
  w0b[1] = cvtpk(acc[6]*inv,  acc[7]*inv);
  w1a[0] = cvtpk(acc[8]*inv,  acc[9]*inv);
  w1a[1] = cvtpk(acc[10]*inv, acc[11]*inv);
  w1b[0] = cvtpk(acc[12]*inv, acc[13]*inv);
  w1b[1] = cvtpk(acc[14]*inv, acc[15]*inv);
  *(uint2v*)(ao)      = w0;
  *(uint2v*)(ao + 4)  = w0b;
  *(uint2v*)(ao + 8)  = w1a;
  *(uint2v*)(ao + 12) = w1b;
}

extern "C" void kernel_launch(void* const* d_in, const int* in_sizes, int n_in,
                              void* d_out, int out_size, void* d_ws, size_t ws_size,
                              hipStream_t stream) {
  const float* x  = (const float*)d_in[0];
  const float* Wq = (const float*)d_in[3];
  const float* Wk = (const float*)d_in[4];
  const float* Wv = (const float*)d_in[5];
  const float* Wo = (const float*)d_in[6];
  float* out = (float*)d_out;

  unsigned short* ws  = (unsigned short*)d_ws;
  unsigned short* xb  = ws;                          // 4096x1024 bf16 (dead after k_qkv)
  unsigned short* wqt = xb  + (size_t)BS_ * D_;      // 1024x1024 (dead after k_qkv)
  unsigned short* wkt = wqt + (size_t)D_ * D_;       // (dead after k_qkv)
  unsigned short* wvt = wkt + (size_t)D_ * D_;       // (dead after k_qkv)
  unsigned short* wot = wvt + (size_t)D_ * D_;       // ALIVE until k_out
  unsigned short* Qb  = wot + (size_t)D_ * D_;       // 4096x1024
  unsigned short* Kb  = Qb  + (size_t)BS_ * D_;
  unsigned short* Vtb = Kb  + (size_t)BS_ * D_;      // (b,h,hd,s)
  unsigned short* AO  = Vtb + (size_t)BS_ * D_;
  // Opart/ML live in the dead xb+wqt+wkt+wvt region (14.68 MB):
  //   Opart: 1664 slots x 4096 shorts = 13.0 MB;  ML: 1664x64 f32 = 416 KB after it.
  unsigned short* Opart = xb;
  float* ML = (float*)(xb + (size_t)1664 * 4096);

  k_prep<<<3072, 256, 0, stream>>>(x, xb, Wq, Wk, Wv, Wo, wqt, wkt, wvt, wot);
  k_qkv<<<dim3(32, 8, 3), 256, 0, stream>>>(xb, wqt, wkt, wvt, Qb, Kb, Vtb);
  k_attn<<<dim3(32, 63), 256, 0, stream>>>(Qb, Kb, Vtb, AO, Opart, ML);
  k_comb<<<dim3(21, 32), 256, 0, stream>>>(Opart, ML, AO);
  k_out<<<dim3(32, 16), 256, 0, stream>>>(AO, wot, out);
}

// Round 20
// 99.039 us; speedup vs baseline: 1.0114x; 1.0114x over previous
//
#include <hip/hip_runtime.h>
#include <hip/hip_bf16.h>

#define B_  2
#define S_  2048
#define D_  1024
#define H_  16
#define HD_ 64
#define BS_ (B_*S_)   // 4096

typedef __attribute__((ext_vector_type(8))) short bf16x8;
typedef __attribute__((ext_vector_type(4))) float f32x4;
typedef __attribute__((ext_vector_type(4))) float float4v;
typedef __attribute__((ext_vector_type(4))) unsigned short ushort4v;
typedef __attribute__((ext_vector_type(2))) unsigned int uint2v;

// longest-first dispatch table for attn work items: (qb, chunk) with chunk 0/1 = kv-half,
// 2 = whole range. All items <= 16 kv-tiles (uniform-ish) -> LPT packing via HW refill.
__constant__ unsigned char TQ[48] = {31,31,30,15, 30,29,29,28,14, 28,27,27,26,13,
                                     26,25,25,24,12, 24,23,23,22,11, 22,21,21,20,10,
                                     20,19,19,18,9, 18,17,17,16,8, 16,7, 6,5,4,3,2,1,0};
__constant__ unsigned char TH[48] = {0,1,1,2, 0,0,1,1,2, 0,0,1,1,2,
                                     0,0,1,1,2, 0,0,1,1,2, 0,0,1,1,2,
                                     0,0,1,1,2, 0,0,1,1,2, 0,2, 2,2,2,2,2,2,2};

__device__ __forceinline__ unsigned short f2bf(float f) {
  union { float f; unsigned int u; } v; v.f = f;
  unsigned int u = v.u;
  return (unsigned short)((u + 0x7fffu + ((u >> 16) & 1u)) >> 16);  // RNE
}
__device__ __forceinline__ float bf2f(unsigned short u) {
  union { unsigned int i; float f; } v; v.i = ((unsigned int)u) << 16; return v.f;
}
__device__ __forceinline__ unsigned int cvtpk(float lo, float hi) {
  unsigned int r;
  asm("v_cvt_pk_bf16_f32 %0, %1, %2" : "=v"(r) : "v"(lo), "v"(hi));
  return r;
}

// cross-lane row swaps via permlane (VALU pipe; R6-R12 bench-proven helpers).
__device__ __forceinline__ void plswap16u(unsigned int& a, unsigned int& b) {
#if __has_builtin(__builtin_amdgcn_permlane16_swap)
  uint2v r = __builtin_amdgcn_permlane16_swap(a, b, false, false);
  a = r[0]; b = r[1];
#else
  asm volatile("v_permlane16_swap_b32 %0, %1" : "+v"(a), "+v"(b));
#endif
}
__device__ __forceinline__ void plswap32u(unsigned int& a, unsigned int& b) {
#if __has_builtin(__builtin_amdgcn_permlane32_swap)
  uint2v r = __builtin_amdgcn_permlane32_swap(a, b, false, false);
  a = r[0]; b = r[1];
#else
  asm volatile("v_permlane32_swap_b32 %0, %1" : "+v"(a), "+v"(b));
#endif
}

__device__ __forceinline__ void gload16(const void* g, void* l) {
  __builtin_amdgcn_global_load_lds((const __attribute__((address_space(1))) void*)g,
                                   (__attribute__((address_space(3))) void*)l, 16, 0, 0);
}

__device__ __forceinline__ f32x4 mfma16(bf16x8 a, bf16x8 b, f32x4 c) {
  return __builtin_amdgcn_mfma_f32_16x16x32_bf16(a, b, c, 0, 0, 0);
}

// ---------------- merged prep: x fp32->bf16 (blocks 0..2047) + W transpose-convert ----------------
__global__ __launch_bounds__(256) void k_prep(const float* __restrict__ x, unsigned short* __restrict__ xb,
                                              const float* __restrict__ w0, const float* __restrict__ w1,
                                              const float* __restrict__ w2, const float* __restrict__ w3,
                                              unsigned short* __restrict__ o0, unsigned short* __restrict__ o1,
                                              unsigned short* __restrict__ o2, unsigned short* __restrict__ o3) {
  const int bid = blockIdx.x;
  if (bid < 2048) {                            // convert part
    int i = bid * 256 + threadIdx.x;
    float4v a = ((const float4v*)x)[2*i];
    float4v b = ((const float4v*)x)[2*i + 1];
    union { bf16x8 v; unsigned short u[8]; } o;
#pragma unroll
    for (int j = 0; j < 4; ++j) { o.u[j] = f2bf(a[j]); o.u[4+j] = f2bf(b[j]); }
    ((bf16x8*)xb)[i] = o.v;
    return;
  }
  // weight transpose part: W (K x N) f32 -> Wt (N x K) bf16
  const int wid = bid - 2048;
  const int xx = wid & 15, yy = (wid >> 4) & 15, zz = wid >> 8;
  const float* w = zz == 0 ? w0 : zz == 1 ? w1 : zz == 2 ? w2 : w3;
  unsigned short* o = zz == 0 ? o0 : zz == 1 ? o1 : zz == 2 ? o2 : o3;
  __shared__ unsigned short til[64][68];
  const int n0 = xx * 64, k0 = yy * 64;
  const int t = threadIdx.x, r = t >> 4, c4 = t & 15;
#pragma unroll
  for (int i = 0; i < 4; ++i) {
    float4v v = *(const float4v*)(w + (size_t)(k0 + i*16 + r) * D_ + n0 + c4*4);
#pragma unroll
    for (int j = 0; j < 4; ++j) til[i*16 + r][c4*4 + j] = f2bf(v[j]);
  }
  __syncthreads();
#pragma unroll
  for (int i = 0; i < 4; ++i) {
    ushort4v u;
#pragma unroll
    for (int j = 0; j < 4; ++j) u[j] = til[c4*4 + j][i*16 + r];
    *(ushort4v*)(o + (size_t)(n0 + i*16 + r) * D_ + k0 + c4*4) = u;
  }
}

// ---------------- GEMM: A (M x K) bf16, Bt (N x K) bf16 -> C (M x N) ----------------
// LDS tiles passed in from the kernel (single allocation; R10 fix for 2x instantiation).
template <int MODE, typename OutT>
__device__ __forceinline__ void gemm_body(const unsigned short* __restrict__ A,
                                          const unsigned short* __restrict__ Bt,
                                          OutT* __restrict__ C,
                                          unsigned short* As, unsigned short* Bs,
                                          int M, int N, int K, int mblk, int nblk) {
  const int tid = threadIdx.x;
  const int w = tid >> 6, lane = tid & 63;
  const int lg = lane >> 4, li = lane & 15;
  const int m0 = mblk * 128, n0 = nblk * 128;
  const int wr = (w >> 1) * 64, wc = (w & 1) * 64;
  f32x4 acc[4][4] = {};
  for (int kt = 0; kt < K; kt += 64) {
#pragma unroll
    for (int i = 0; i < 4; ++i) {
      int c = (i*4 + w) * 64 + lane;           // 0..1023, 16B chunks
      int r = c >> 3, kc = c & 7;
      int off = ((kc ^ (r & 7)) << 3);         // pre-swizzled global source (rule #21)
      gload16(A  + (size_t)(m0 + r) * K + kt + off, (char*)As + (i*4 + w) * 1024);
      gload16(Bt + (size_t)(n0 + r) * K + kt + off, (char*)Bs + (i*4 + w) * 1024);
    }
    __syncthreads();
#pragma unroll
    for (int ks = 0; ks < 2; ++ks) {
      bf16x8 af[4], bfr[4];
#pragma unroll
      for (int m = 0; m < 4; ++m) {
        int rr = wr + m*16 + li;
        int ch = (ks*4 + lg) ^ (rr & 7);
        af[m] = *(const bf16x8*)((const char*)As + rr*128 + ch*16);
      }
#pragma unroll
      for (int n = 0; n < 4; ++n) {
        int rr = wc + n*16 + li;
        int ch = (ks*4 + lg) ^ (rr & 7);
        bfr[n] = *(const bf16x8*)((const char*)Bs + rr*128 + ch*16);
      }
#pragma unroll
      for (int m = 0; m < 4; ++m)
#pragma unroll
        for (int n = 0; n < 4; ++n)
          acc[m][n] = mfma16(af[m], bfr[n], acc[m][n]);
    }
    __syncthreads();
  }
#pragma unroll
  for (int m = 0; m < 4; ++m)
#pragma unroll
    for (int n = 0; n < 4; ++n) {
      if (MODE == 2) {                         // V: store transposed into (b,h,hd,s)
        int gr = m0 + wr + m*16 + lg*4;        // rows gr..gr+3 (s-consecutive)
        int gc = n0 + wc + n*16 + li;          // col = h*64 + d
        int bb = gr >> 11, ss = gr & 2047, hh = gc >> 6, dd = gc & 63;
        unsigned short* p = (unsigned short*)C + ((size_t)((bb*H_ + hh)*HD_ + dd)) * S_ + ss;
        uint2v o2;
        o2[0] = cvtpk(acc[m][n][0], acc[m][n][1]);
        o2[1] = cvtpk(acc[m][n][2], acc[m][n][3]);
        *(uint2v*)p = o2;
      } else {
#pragma unroll
        for (int j = 0; j < 4; ++j) {
          int row = m0 + wr + m*16 + lg*4 + j; // HW-verified C layout (m89)
          int col = n0 + wc + n*16 + li;
          if (MODE == 1) ((float*)C)[(size_t)row * N + col] = acc[m][n][j];
          else ((unsigned short*)C)[(size_t)row * N + col] = f2bf(acc[m][n][j]);
        }
      }
    }
}

__global__ __launch_bounds__(256, 3) void k_qkv(const unsigned short* __restrict__ xb,
    const unsigned short* __restrict__ wqt, const unsigned short* __restrict__ wkt,
    const unsigned short* __restrict__ wvt,
    unsigned short* __restrict__ Qb, unsigned short* __restrict__ Kb, unsigned short* __restrict__ Vtb) {
  __shared__ unsigned short As[128 * 64];
  __shared__ unsigned short Bs[128 * 64];
  const int z = blockIdx.z;
  if (z == 2) {
    gemm_body<2, unsigned short>(xb, wvt, Vtb, As, Bs, BS_, D_, D_, blockIdx.x, blockIdx.y);
  } else {
    gemm_body<0, unsigned short>(xb, z ? wkt : wqt, z ? Kb : Qb, As, Bs, BS_, D_, D_, blockIdx.x, blockIdx.y);
  }
}

// ---------------- out GEMM: 128x64 tile -> grid (32,16) = 512 blocks = 2/CU (R18-proven) --------
__global__ __launch_bounds__(256, 2) void k_out(const unsigned short* __restrict__ AO,
                                                const unsigned short* __restrict__ wot,
                                                float* __restrict__ out) {
  __shared__ unsigned short As[128 * 64];     // 16KB
  __shared__ unsigned short Bs[64 * 64];      // 8KB
  const int tid = threadIdx.x;
  const int w = tid >> 6, lane = tid & 63;
  const int lg = lane >> 4, li = lane & 15;
  const int m0 = blockIdx.x * 128, n0 = blockIdx.y * 64;
  f32x4 acc[2][4] = {};
  for (int kt = 0; kt < D_; kt += 64) {
#pragma unroll
    for (int i = 0; i < 4; ++i) {             // A: 1024 chunks (gemm_body pattern)
      int c = (i*4 + w) * 64 + lane;
      int r = c >> 3, kc = c & 7;
      int off = ((kc ^ (r & 7)) << 3);
      gload16(AO + (size_t)(m0 + r) * D_ + kt + off, (char*)As + (i*4 + w) * 1024);
    }
#pragma unroll
    for (int i = 0; i < 2; ++i) {             // B: 512 chunks (attn K-staging pattern)
      int c = (i*4 + w) * 64 + lane;
      int r = c >> 3, kc = c & 7;
      int off = ((kc ^ (r & 7)) << 3);
      gload16(wot + (size_t)(n0 + r) * D_ + kt + off, (char*)Bs + (i*4 + w) * 1024);
    }
    __syncthreads();
#pragma unroll
    for (int ks = 0; ks < 2; ++ks) {
      bf16x8 af[2], bfr[4];
#pragma unroll
      for (int m = 0; m < 2; ++m) {
        int rr = w*32 + m*16 + li;
        int ch = (ks*4 + lg) ^ (rr & 7);
        af[m] = *(const bf16x8*)((const char*)As + rr*128 + ch*16);
      }
#pragma unroll
      for (int n = 0; n < 4; ++n) {
        int rr = n*16 + li;
        int ch = (ks*4 + lg) ^ (rr & 7);
        bfr[n] = *(const bf16x8*)((const char*)Bs + rr*128 + ch*16);
      }
#pragma unroll
      for (int m = 0; m < 2; ++m)
#pragma unroll
        for (int n = 0; n < 4; ++n)
          acc[m][n] = mfma16(af[m], bfr[n], acc[m][n]);
    }
    __syncthreads();
  }
#pragma unroll
  for (int m = 0; m < 2; ++m)
#pragma unroll
    for (int n = 0; n < 4; ++n)
#pragma unroll
      for (int j = 0; j < 4; ++j) {
        int row = m0 + w*32 + m*16 + lg*4 + j; // HW-verified C layout (m89)
        int col = n0 + n*16 + li;
        out[(size_t)row * D_ + col] = acc[m][n][j];
      }
}

// ---------------- flash attention, causal — split-kv, in-register P, l via MFMA (R15-proven) ----
__global__ __launch_bounds__(256, 5) void k_attn(const unsigned short* __restrict__ Q,
                                                 const unsigned short* __restrict__ K,
                                                 const unsigned short* __restrict__ Vt,
                                                 unsigned short* __restrict__ AO,
                                                 unsigned short* __restrict__ Opart,
                                                 float* __restrict__ ML) {
  __shared__ unsigned short Ks[2 * 64 * 64];  // [buf][kv][hd], chunk-swizzled
  __shared__ unsigned short Vs[2 * 64 * 64];  // [buf][hd][kv], chunk-swizzled
  const int bh = blockIdx.x;                  // XCD = linear%8 -> all items of a head share L2
  const int y = blockIdx.y;
  const int qb = TQ[y], ch = TH[y];           // chunk: 0 = low half, 1 = high half (diag), 2 = whole
  const int n = qb + 1, ka = n >> 1;
  const int kt0 = (ch == 1) ? ka : 0;
  const int kt1 = (ch == 0) ? ka : n;
  const bool split = (ch != 2);
  const int b = bh >> 4, h = bh & 15;
  const int tid = threadIdx.x, w = tid >> 6, lane = tid & 63;
  const int lg = lane >> 4, li = lane & 15;
  const float SC2 = 0.18033688f;              // (1/sqrt(64)) * log2(e)

  // ones A-fragment for the l contraction (bf16 1.0 = 0x3f80)
  union { bf16x8 v; unsigned short u[8]; } onesu;
#pragma unroll
  for (int j = 0; j < 8; ++j) onesu.u[j] = 0x3f80;
  const bf16x8 onesv = onesu.v;

  // Q fragment (B-operand): row = q = li, k-chunks lg*8 (+0 / +32); pre-scaled by SC2.
  const int qglob = qb*64 + w*16 + li;
  const unsigned short* qptr = Q + (size_t)(b*S_ + qglob) * D_ + h*HD_;
  union { bf16x8 v; unsigned short u[8]; } q0u, q1u;
  q0u.v = *(const bf16x8*)(qptr + lg*8);
  q1u.v = *(const bf16x8*)(qptr + 32 + lg*8);
#pragma unroll
  for (int j = 0; j < 8; ++j) {
    q0u.u[j] = f2bf(bf2f(q0u.u[j]) * SC2);
    q1u.u[j] = f2bf(bf2f(q1u.u[j]) * SC2);
  }
  const bf16x8 qf0 = q0u.v, qf1 = q1u.v;

  // K-fragment LDS offsets: row=li (within kj block), chunk ks*4+lg
  int kfoff[2];
#pragma unroll
  for (int ks = 0; ks < 2; ++ks)
    kfoff[ks] = li*128 + (((ks*4 + lg) ^ (li & 7)) << 4);

  // staging: per-lane global offsets + advancing base pointers (R4-proven 4-wave split)
  int kofs[2], vofs[2], lofs[2];
#pragma unroll
  for (int i = 0; i < 2; ++i) {
    int c = (i*4 + w) * 64 + lane;            // 0..511, 16B chunks
    int r = c >> 3, kc = c & 7;
    int off = ((kc ^ (r & 7)) << 3);          // pre-swizzled global source (rule #21)
    kofs[i] = r * D_ + off;
    vofs[i] = r * S_ + off;
    lofs[i] = (i*4 + w) * 1024;
  }
  const unsigned short* kg = K  + (size_t)(b*S_ + kt0*64) * D_ + h*HD_;  // += 64*D_ per tile
  const unsigned short* vg = Vt + (size_t)bh * HD_ * S_ + kt0*64;        // += 64 per tile

  f32x4 oacc[4] = {};                          // oacc[nn][j] = O[q=li][d=nn*16+lg*4+j], unnormalized
  f32x4 lacc = {};                             // lacc[j] = l[q=li] (all j equal)

  auto stage = [&](int bsel, const unsigned short* kp, const unsigned short* vp) {
    char* KsB = (char*)Ks + bsel * 8192;
    char* VsB = (char*)Vs + bsel * 8192;
#pragma unroll
    for (int i = 0; i < 2; ++i) {
      gload16(kp + kofs[i], KsB + lofs[i]);
      gload16(vp + vofs[i], VsB + lofs[i]);
    }
  };

  stage(0, kg, vg);
  __syncthreads();

  for (int kt = kt0; kt < kt1; ++kt) {
    const int cur = (kt - kt0) & 1;
    if (kt + 1 < kt1) {                        // prefetch overlaps this tile's compute
      kg += 64 * D_; vg += 64;
      stage(cur ^ 1, kg, vg);
    }
    const char* KsB = (const char*)Ks + cur * 8192;
    const char* VsB = (const char*)Vs + cur * 8192;

    // S^T = K Q^T : sc[kj][j] = S[q=li][kv=kj*16+lg*4+j]  (log2-scaled)
    f32x4 sc[4];
    __builtin_amdgcn_s_setprio(1);
#pragma unroll
    for (int kj = 0; kj < 4; ++kj) {
      f32x4 t = {};
      t = mfma16(*(const bf16x8*)(KsB + kj*2048 + kfoff[0]), qf0, t);
      t = mfma16(*(const bf16x8*)(KsB + kj*2048 + kfoff[1]), qf1, t);
      sc[kj] = t;
    }
    __builtin_amdgcn_s_setprio(0);

    if (kt == qb) {                            // causal mask (diag tile; only in ch 1/2)
      const int qloc = w*16 + li;
#pragma unroll
      for (int kj = 0; kj < 4; ++kj)
#pragma unroll
        for (int j = 0; j < 4; ++j)
          if (kj*16 + lg*4 + j > qloc) sc[kj][j] = -1e30f;
    }

    // softmax weights, no max subtraction (bounded scores): P = exp2(S2) <= 2^9
    f32x4 pvv[4];
#pragma unroll
    for (int kj = 0; kj < 4; ++kj)
#pragma unroll
      for (int j = 0; j < 4; ++j)
        pvv[kj][j] = exp2f(sc[kj][j]);         // masked entries underflow to 0

    // P -> bf16 dwords d[kj][p] -> in-register fragment via permlane swaps (R8-proven)
    unsigned int d00 = cvtpk(pvv[0][0], pvv[0][1]), d01 = cvtpk(pvv[0][2], pvv[0][3]);
    unsigned int d10 = cvtpk(pvv[1][0], pvv[1][1]), d11 = cvtpk(pvv[1][2], pvv[1][3]);
    unsigned int d20 = cvtpk(pvv[2][0], pvv[2][1]), d21 = cvtpk(pvv[2][2], pvv[2][3]);
    unsigned int d30 = cvtpk(pvv[3][0], pvv[3][1]), d31 = cvtpk(pvv[3][2], pvv[3][3]);
    plswap32u(d00, d10); plswap16u(d00, d10);
    plswap32u(d01, d11); plswap16u(d01, d11);
    plswap32u(d20, d30); plswap16u(d20, d30);
    plswap32u(d21, d31); plswap16u(d21, d31);
    union { bf16x8 v; unsigned int d[4]; } p0, p1;
    p0.d[0] = d00; p0.d[1] = d01; p0.d[2] = d10; p0.d[3] = d11;
    p1.d[0] = d20; p1.d[1] = d21; p1.d[2] = d30; p1.d[3] = d31;

    // O^T += V^T P^T ; l += ones . P  (matrix pipe computes the row-sums too)
    __builtin_amdgcn_s_setprio(1);
    lacc = mfma16(onesv, p0.v, lacc);
    lacc = mfma16(onesv, p1.v, lacc);
#pragma unroll
    for (int nn = 0; nn < 4; ++nn) {
      int vr = nn*16 + li;
      int ch0 = lg ^ (vr & 7), ch1 = (4 + lg) ^ (vr & 7);
      oacc[nn] = mfma16(*(const bf16x8*)(VsB + vr*128 + ch0*16), p0.v, oacc[nn]);
      oacc[nn] = mfma16(*(const bf16x8*)(VsB + vr*128 + ch1*16), p1.v, oacc[nn]);
    }
    __builtin_amdgcn_s_setprio(0);
    __syncthreads();   // drains prefetch vmcnt + publishes; next iter reads buf^1
  }

  // epilogue — l is already fully reduced per-lane (lacc[0] == row-sum for q=li)
  const float l = lacc[0];
  if (!split) {                                // direct: normalize + store bf16
    const float inv = 1.0f / l;
    unsigned short* aorow = AO + (size_t)(b*S_ + qglob) * D_ + h*HD_;
#pragma unroll
    for (int nn = 0; nn < 4; ++nn) {
      uint2v o2;
      o2[0] = cvtpk(oacc[nn][0] * inv, oacc[nn][1] * inv);
      o2[1] = cvtpk(oacc[nn][2] * inv, oacc[nn][3] * inv);
      *(uint2v*)(aorow + nn*16 + lg*4) = o2;
    }
  } else {                                     // partial: unnormalized O bf16 + l f32
    const int slot = ((bh << 4) + (qb - 16)) * 2 + ch;
    unsigned short* ob = Opart + (size_t)slot * 4096 + (w*16 + li) * 64;
#pragma unroll
    for (int nn = 0; nn < 4; ++nn) {
      uint2v o2;
      o2[0] = cvtpk(oacc[nn][0], oacc[nn][1]);
      o2[1] = cvtpk(oacc[nn][2], oacc[nn][3]);
      *(uint2v*)(ob + nn*16 + lg*4) = o2;
    }
    if (lg == 0) ML[slot*64 + (w*16 + li)] = l;
  }
}

// ---------------- combine split-kv partials: AO[qb>=16] = (o0+o1)/(l0+l1) ----------------
__global__ __launch_bounds__(256) void k_comb(const unsigned short* __restrict__ Opart,
                                              const float* __restrict__ ML,
                                              unsigned short* __restrict__ AO) {
  const int qx = blockIdx.x;                  // 0..15 -> qb = 16+qx
  const int bh = blockIdx.y;                  // 0..31
  const int b = bh >> 4, h = bh & 15;
  const int slot0 = ((bh << 4) + qx) * 2;
  const int tid = threadIdx.x;
  const int q = tid >> 2, dg = (tid & 3) * 16;
  const float l0 = ML[slot0*64 + q], l1 = ML[(slot0+1)*64 + q];
  const float inv = 1.0f / (l0 + l1);
  const unsigned short* o0 = Opart + (size_t)slot0 * 4096 + q*64 + dg;
  const unsigned short* o1 = o0 + 4096;
  union { bf16x8 v; unsigned short u[8]; } x0a, x0b, x1a, x1b;
  x0a.v = *(const bf16x8*)o0;  x0b.v = *(const bf16x8*)(o0 + 8);
  x1a.v = *(const bf16x8*)o1;  x1b.v = *(const bf16x8*)(o1 + 8);
  unsigned short* ao = AO + (size_t)(b*S_ + (16 + qx)*64 + q) * D_ + h*HD_ + dg;
  uint2v w0, w0b, w1a, w1b;
  w0[0]  = cvtpk((bf2f(x0a.u[0]) + bf2f(x1a.u[0])) * inv, (bf2f(x0a.u[1]) + bf2f(x1a.u[1])) * inv);
  w0[1]  = cvtpk((bf2f(x0a.u[2]) + bf2f(x1a.u[2])) * inv, (bf2f(x0a.u[3]) + bf2f(x1a.u[3])) * inv);
  w0b[0] = cvtpk((bf2f(x0a.u[4]) + bf2f(x1a.u[4])) * inv, (bf2f(x0a.u[5]) + bf2f(x1a.u[5])) * inv);
  w0b[1] = cvtpk((bf2f(x0a.u[6]) + bf2f(x1a.u[6])) * inv, (bf2f(x0a.u[7]) + bf2f(x1a.u[7])) * inv);
  w1a[0] = cvtpk((bf2f(x0b.u[0]) + bf2f(x1b.u[0])) * inv, (bf2f(x0b.u[1]) + bf2f(x1b.u[1])) * inv);
  w1a[1] = cvtpk((bf2f(x0b.u[2]) + bf2f(x1b.u[2])) * inv, (bf2f(x0b.u[3]) + bf2f(x1b.u[3])) * inv);
  w1b[0] = cvtpk((bf2f(x0b.u[4]) + bf2f(x1b.u[4])) * inv, (bf2f(x0b.u[5]) + bf2f(x1b.u[5])) * inv);
  w1b[1] = cvtpk((bf2f(x0b.u[6]) + bf2f(x1b.u[6])) * inv, (bf2f(x0b.u[7]) + bf2f(x1b.u[7])) * inv);
  *(uint2v*)(ao)      = w0;
  *(uint2v*)(ao + 4)  = w0b;
  *(uint2v*)(ao + 8)  = w1a;
  *(uint2v*)(ao + 12) = w1b;
}

extern "C" void kernel_launch(void* const* d_in, const int* in_sizes, int n_in,
                              void* d_out, int out_size, void* d_ws, size_t ws_size,
                              hipStream_t stream) {
  const float* x  = (const float*)d_in[0];
  const float* Wq = (const float*)d_in[3];
  const float* Wk = (const float*)d_in[4];
  const float* Wv = (const float*)d_in[5];
  const float* Wo = (const float*)d_in[6];
  float* out = (float*)d_out;

  unsigned short* ws  = (unsigned short*)d_ws;
  unsigned short* xb  = ws;                          // 4096x1024 bf16 (dead after k_qkv -> Opart)
  unsigned short* wqt = xb  + (size_t)BS_ * D_;      // 1024x1024 (dead after k_qkv -> ML)
  unsigned short* wkt = wqt + (size_t)D_ * D_;
  unsigned short* wvt = wkt + (size_t)D_ * D_;
  unsigned short* wot = wvt + (size_t)D_ * D_;
  unsigned short* Qb  = wot + (size_t)D_ * D_;       // 4096x1024
  unsigned short* Kb  = Qb  + (size_t)BS_ * D_;
  unsigned short* Vtb = Kb  + (size_t)BS_ * D_;      // (b,h,hd,s)
  unsigned short* AO  = Vtb + (size_t)BS_ * D_;
  unsigned short* Opart = xb;                        // 1024 slots x 64x64 bf16 = 8.4MB (== xb size)
  float* ML = (float*)wqt;                           // 1024 slots x 64 f32 = 256KB

  k_prep<<<3072, 256, 0, stream>>>(x, xb, Wq, Wk, Wv, Wo, wqt, wkt, wvt, wot);
  k_qkv<<<dim3(32, 8, 3), 256, 0, stream>>>(xb, wqt, wkt, wvt, Qb, Kb, Vtb);
  k_attn<<<dim3(32, 48), 256, 0, stream>>>(Qb, Kb, Vtb, AO, Opart, ML);
  k_comb<<<dim3(16, 32), 256, 0, stream>>>(Opart, ML, AO);
  k_out<<<dim3(32, 16), 256, 0, stream>>>(AO, wot, out);
}